// Round 6
// baseline (585.881 us; speedup 1.0000x reference)
//
#include <hip/hip_runtime.h>

// PointNet++-style decoder forward: 3 levels of {knn_interpolate -> concat ->
// Lin+BN+ReLU -> residual Lin+BN+ReLU}. All fp32. Single batch.

#define EPS_BN 1e-5f
#define EPS_W  1e-16f

// ---- L2 KNN spatial grid parameters (sources = 8192 Gaussian pts) ---------
#define GRD    52
#define GLO   -6.5f
#define GH     0.25f
#define GIH    4.0f
#define NCELLS (GRD * GRD * GRD)   // 140608
#define RMAX   5

typedef unsigned long long u64;

// ---------------------------------------------------------------------------
// Brute KNN pass 1 (levels 0,1): split over sources. Block = 256 threads x
// TPT targets vs one source chunk in LDS. Branchless sorted top-3.
// ---------------------------------------------------------------------------
template<int TPT>
__global__ __launch_bounds__(256)
void knn_part(const float* __restrict__ pos_s, const float* __restrict__ pos_t,
              int Ns, int Nt, int nsplit,
              float* __restrict__ cand_d, int* __restrict__ cand_i)
{
  __shared__ float4 sp[512];

  const int tb  = blockIdx.x;
  const int spl = blockIdx.y;
  const int chunk = Ns / nsplit;
  const int cs = spl * chunk;

  float tx[TPT], ty[TPT], tz[TPT];
  float d0[TPT], d1[TPT], d2[TPT];
  int   j0[TPT], j1[TPT], j2[TPT];

#pragma unroll
  for (int q = 0; q < TPT; ++q) {
    int t = tb * 256 * TPT + q * 256 + threadIdx.x;
    tx[q] = pos_t[3 * t + 0];
    ty[q] = pos_t[3 * t + 1];
    tz[q] = pos_t[3 * t + 2];
    d0[q] = 3.4e38f; d1[q] = 3.4e38f; d2[q] = 3.4e38f;
    j0[q] = 0; j1[q] = 0; j2[q] = 0;
  }

  for (int i = threadIdx.x; i < chunk; i += 256) {
    int p = cs + i;
    sp[i] = make_float4(pos_s[3 * p], pos_s[3 * p + 1], pos_s[3 * p + 2], 0.f);
  }
  __syncthreads();

#pragma unroll 4
  for (int j = 0; j < chunk; ++j) {
    float4 s = sp[j];
    int gj = cs + j;
#pragma unroll
    for (int q = 0; q < TPT; ++q) {
      float dx = tx[q] - s.x, dy = ty[q] - s.y, dz = tz[q] - s.z;
      float nd = fmaf(dz, dz, fmaf(dy, dy, dx * dx));
      int nj = gj;
      bool c = nd < d0[q];
      float td = c ? d0[q] : nd;  int tj = c ? j0[q] : nj;
      d0[q] = c ? nd : d0[q];     j0[q] = c ? nj : j0[q];
      nd = td; nj = tj;
      c = nd < d1[q];
      td = c ? d1[q] : nd;        tj = c ? j1[q] : nj;
      d1[q] = c ? nd : d1[q];     j1[q] = c ? nj : j1[q];
      nd = td; nj = tj;
      c = nd < d2[q];
      d2[q] = c ? nd : d2[q];     j2[q] = c ? nj : j2[q];
    }
  }

#pragma unroll
  for (int q = 0; q < TPT; ++q) {
    int t = tb * 256 * TPT + q * 256 + threadIdx.x;
    int o = (t * nsplit + spl) * 3;
    cand_d[o + 0] = d0[q]; cand_d[o + 1] = d1[q]; cand_d[o + 2] = d2[q];
    cand_i[o + 0] = j0[q]; cand_i[o + 1] = j1[q]; cand_i[o + 2] = j2[q];
  }
}

// ---------------------------------------------------------------------------
// Merge + gather (all levels): block = 64 targets x 4 channel-groups.
// FROMW=0: merge nsplit partial top-3 lists; FROMW=1: read widx (L2 path).
// Block 0 zeroes the BN stats accumulators for the following GEMMs.
// ---------------------------------------------------------------------------
template<int CS, int FROMW>
__global__ __launch_bounds__(256)
void merge_gather(const float* __restrict__ cand_d, const int* __restrict__ cand_i,
                  int nsplit, const float* __restrict__ xs,
                  float* __restrict__ up, int Nt,
                  float* __restrict__ stats0, const float* __restrict__ widx)
{
  if (blockIdx.x == 0) {
    for (int i = threadIdx.x; i < 1024; i += 256) stats0[i] = 0.f;
  }

  int t  = blockIdx.x * 64 + (threadIdx.x >> 2);
  int cg = threadIdx.x & 3;

  float w0, w1, w2; int i0, i1, i2;
  if (FROMW) {
    float4 wv = *(const float4*)&widx[(size_t)t * 8];
    float4 iv = *(const float4*)&widx[(size_t)t * 8 + 4];
    w0 = wv.x; w1 = wv.y; w2 = wv.z;
    i0 = (int)__float_as_uint(iv.x);
    i1 = (int)__float_as_uint(iv.y);
    i2 = (int)__float_as_uint(iv.z);
  } else {
    float e0 = 3.5e38f, e1 = 3.5e38f, e2 = 3.5e38f;
    i0 = 0; i1 = 0; i2 = 0;
    int o = t * nsplit * 3;
    for (int c = 0; c < nsplit * 3; ++c) {
      float d = cand_d[o + c];
      int   i = cand_i[o + c];
      if (d < e2) {
        if (d < e1) {
          e2 = e1; i2 = i1;
          if (d < e0) { e1 = e0; i1 = i0; e0 = d; i0 = i; }
          else        { e1 = d;  i1 = i; }
        } else { e2 = d; i2 = i; }
      }
    }
    w0 = 1.f / fmaxf(e0, EPS_W);
    w1 = 1.f / fmaxf(e1, EPS_W);
    w2 = 1.f / fmaxf(e2, EPS_W);
    float inv = 1.f / (w0 + w1 + w2);
    w0 *= inv; w1 *= inv; w2 *= inv;
  }

  const float4* r0 = (const float4*)(xs + (size_t)i0 * CS);
  const float4* r1 = (const float4*)(xs + (size_t)i1 * CS);
  const float4* r2 = (const float4*)(xs + (size_t)i2 * CS);
  float4* ou = (float4*)(up + (size_t)t * CS);
  const int F4 = CS / 4;
#pragma unroll 4
  for (int k = 0; k < F4 / 4; ++k) {
    int f = cg + 4 * k;
    float4 a = r0[f], b = r1[f], d = r2[f], rr;
    rr.x = w0 * a.x + w1 * b.x + w2 * d.x;
    rr.y = w0 * a.y + w1 * b.y + w2 * d.y;
    rr.z = w0 * a.z + w1 * b.z + w2 * d.z;
    rr.w = w0 * a.w + w1 * b.w + w2 * d.w;
    ou[f] = rr;
  }
}

// ---------------------------------------------------------------------------
// Grid build (L2). Fused source/target variants via blockIdx.y.
// ---------------------------------------------------------------------------
__device__ __forceinline__ int cell_coord(float v) {
  return min(max((int)floorf((v - GLO) * GIH), 0), GRD - 1);
}

__global__ __launch_bounds__(256)
void grid_count2(const float* __restrict__ ps, int ns, int* __restrict__ cnt,
                 int* __restrict__ pcell,
                 const float* __restrict__ pt, int nt, int* __restrict__ tcnt,
                 int* __restrict__ tpcell)
{
  int i = blockIdx.x * 256 + threadIdx.x;
  const float* p; int n; int* c; int* pc;
  if (blockIdx.y == 0) { p = ps; n = ns; c = cnt;  pc = pcell; }
  else                 { p = pt; n = nt; c = tcnt; pc = tpcell; }
  if (i >= n) return;
  int cx = cell_coord(p[3 * i + 0]);
  int cy = cell_coord(p[3 * i + 1]);
  int cz = cell_coord(p[3 * i + 2]);
  int cid = (cz * GRD + cy) * GRD + cx;
  pc[i] = cid;
  atomicAdd(&c[cid], 1);
}

__global__ __launch_bounds__(256)
void grid_scan1(const int* __restrict__ cntA, int* __restrict__ ofspA,
                int* __restrict__ auxA,
                const int* __restrict__ cntB, int* __restrict__ ofspB,
                int* __restrict__ auxB)
{
  const int* cnt; int* ofsp; int* aux;
  if (blockIdx.y == 0) { cnt = cntA; ofsp = ofspA; aux = auxA; }
  else                 { cnt = cntB; ofsp = ofspB; aux = auxB; }
  __shared__ int arr[256];
  int tid = threadIdx.x;
  int c0 = blockIdx.x * 1024 + tid * 4;
  int s0 = (c0 + 0 < NCELLS) ? cnt[c0 + 0] : 0;
  int s1 = (c0 + 1 < NCELLS) ? cnt[c0 + 1] : 0;
  int s2 = (c0 + 2 < NCELLS) ? cnt[c0 + 2] : 0;
  int s3 = (c0 + 3 < NCELLS) ? cnt[c0 + 3] : 0;
  int p1 = s0, p2 = s0 + s1, p3 = p2 + s2, tot = p3 + s3;
  arr[tid] = tot; __syncthreads();
  for (int d = 1; d < 256; d <<= 1) {
    int v = (tid >= d) ? arr[tid - d] : 0;
    __syncthreads();
    arr[tid] += v;
    __syncthreads();
  }
  int excl = arr[tid] - tot;
  if (c0 + 0 < NCELLS) ofsp[c0 + 0] = excl;
  if (c0 + 1 < NCELLS) ofsp[c0 + 1] = excl + p1;
  if (c0 + 2 < NCELLS) ofsp[c0 + 2] = excl + p2;
  if (c0 + 3 < NCELLS) ofsp[c0 + 3] = excl + p3;
  if (tid == 255) aux[blockIdx.x] = arr[255];
}

__global__ __launch_bounds__(256)
void grid_scan2(const int* __restrict__ auxA, int* __restrict__ auxpA,
                const int* __restrict__ auxB, int* __restrict__ auxpB, int nblk)
{
  const int* aux; int* auxp;
  if (blockIdx.x == 0) { aux = auxA; auxp = auxpA; }
  else                 { aux = auxB; auxp = auxpB; }
  __shared__ int arr[256];
  int tid = threadIdx.x;
  int v = (tid < nblk) ? aux[tid] : 0;
  arr[tid] = v; __syncthreads();
  for (int d = 1; d < 256; d <<= 1) {
    int w = (tid >= d) ? arr[tid - d] : 0;
    __syncthreads();
    arr[tid] += w;
    __syncthreads();
  }
  auxp[tid] = arr[tid] - v;   // exclusive
}

// side 0: cursor + cellstart (+sentinel, ovfc=0); side 1: tcursor only.
__global__ __launch_bounds__(256)
void grid_fixup2(const int* __restrict__ ofsp, const int* __restrict__ auxp,
                 int* __restrict__ cursor, int* __restrict__ cellstart,
                 int ns_total,
                 const int* __restrict__ tofsp, const int* __restrict__ tauxp,
                 int* __restrict__ tcursor, int* __restrict__ ovf_cnt)
{
  int i = blockIdx.x * 256 + threadIdx.x;
  if (blockIdx.y == 0) {
    if (i == 0) { *ovf_cnt = 0; cellstart[NCELLS] = ns_total; }
    for (int c = i; c < NCELLS; c += gridDim.x * 256) {
      int v = ofsp[c] + auxp[c >> 10];
      cursor[c] = v;
      cellstart[c] = v;
    }
  } else {
    for (int c = i; c < NCELLS; c += gridDim.x * 256)
      tcursor[c] = tofsp[c] + tauxp[c >> 10];
  }
}

// side 0: scatter source points as float4(pos,idx); side 1: target index sort.
__global__ __launch_bounds__(256)
void grid_scatter2(const float* __restrict__ ps, int ns,
                   const int* __restrict__ pcell, int* __restrict__ cursor,
                   float4* __restrict__ plist,
                   int nt, const int* __restrict__ tpcell,
                   int* __restrict__ tcursor, int* __restrict__ tsorted)
{
  int i = blockIdx.x * 256 + threadIdx.x;
  if (blockIdx.y == 0) {
    if (i >= ns) return;
    int slot = atomicAdd(&cursor[pcell[i]], 1);
    plist[slot] = make_float4(ps[3 * i], ps[3 * i + 1], ps[3 * i + 2],
                              __uint_as_float((unsigned)i));
  } else {
    if (i >= nt) return;
    int slot = atomicAdd(&tcursor[tpcell[i]], 1);
    tsorted[slot] = i;
  }
}

// ---------------------------------------------------------------------------
// L2 KNN search: contiguous x-row ranges (plist cell-sorted), expanding
// shells with exact cube-face lower-bound certification up to r=RMAX.
// u64 keys (dist<<32|idx): scatter-order independent, ties by smaller index
// (jax.lax.top_k stability). No cell scanned twice (duplicate keys would
// corrupt the top-3). Unresolved -> overflow list (exact brute fallback).
// ---------------------------------------------------------------------------
__device__ __forceinline__ void key_insert(u64 nk, u64& k0, u64& k1, u64& k2) {
  bool c = nk < k0; u64 tk = c ? k0 : nk; k0 = c ? nk : k0; nk = tk;
  c = nk < k1; tk = c ? k1 : nk; k1 = c ? nk : k1; nk = tk;
  c = nk < k2; k2 = c ? nk : k2;
}

__global__ __launch_bounds__(256)
void knn_search27(const float* __restrict__ pos_t, int Nt,
                  const int* __restrict__ cellstart,
                  const float4* __restrict__ plist,
                  const int* __restrict__ tsorted,
                  float* __restrict__ widx,
                  int* __restrict__ ovf_cnt, int* __restrict__ ovf)
{
  int gid = blockIdx.x * 256 + threadIdx.x;
  if (gid >= Nt) return;
  int t = tsorted[gid];
  float tx = pos_t[3 * t], ty = pos_t[3 * t + 1], tz = pos_t[3 * t + 2];
  int cx = cell_coord(tx), cy = cell_coord(ty), cz = cell_coord(tz);

  u64 k0 = ~0ULL, k1 = ~0ULL, k2 = ~0ULL;

  auto scan_range = [&](int p0, int p1) {
    for (int p = p0; p < p1; ++p) {
      float4 s = plist[p];
      float dx = tx - s.x, dy = ty - s.y, dz = tz - s.z;
      float d = fmaf(dz, dz, fmaf(dy, dy, dx * dx));
      key_insert(((u64)__float_as_uint(d) << 32) | (u64)__float_as_uint(s.w),
                 k0, k1, k2);
    }
  };

  auto certify = [&](int R) -> bool {
    int xl = max(cx - R, 0), xh = min(cx + R, GRD - 1);
    int yl = max(cy - R, 0), yh = min(cy + R, GRD - 1);
    int zl = max(cz - R, 0), zh = min(cz + R, GRD - 1);
    float m = 1e30f;
    if (xl > 0)       m = fminf(m, tx - (GLO + xl * GH));
    if (xh < GRD - 1) m = fminf(m, (GLO + (xh + 1) * GH) - tx);
    if (yl > 0)       m = fminf(m, ty - (GLO + yl * GH));
    if (yh < GRD - 1) m = fminf(m, (GLO + (yh + 1) * GH) - ty);
    if (zl > 0)       m = fminf(m, tz - (GLO + zl * GH));
    if (zh < GRD - 1) m = fminf(m, (GLO + (zh + 1) * GH) - tz);
    float d2b = __uint_as_float((unsigned)(k2 >> 32));   // NaN if <3 found
    return (m * m * 0.9999f > d2b);                      // NaN -> false
  };

  // Phase 1: 3x3 rows, ranges prefetched into registers (independent loads)
  int xlo = max(cx - 1, 0), xhi = min(cx + 1, GRD - 1);
  int rs[9], re[9];
#pragma unroll
  for (int dz = -1; dz <= 1; ++dz)
#pragma unroll
    for (int dy = -1; dy <= 1; ++dy) {
      int id = (dz + 1) * 3 + (dy + 1);
      int y = cy + dy, z = cz + dz;
      bool ok = ((unsigned)y < GRD) && ((unsigned)z < GRD);
      int base = (z * GRD + y) * GRD;
      rs[id] = ok ? cellstart[base + xlo] : 0;
      re[id] = ok ? cellstart[base + xhi + 1] : 0;
    }
#pragma unroll
  for (int id = 0; id < 9; ++id) scan_range(rs[id], re[id]);

  bool done = certify(1);

  // Shells r=2..RMAX: outer rows (|dy|==r or |dz|==r) span full x range;
  // inner rows add only the two x = cx +- r end caps. No cell re-scanned.
  for (int r = 2; r <= RMAX && !done; ++r) {
    int xl = max(cx - r, 0), xh = min(cx + r, GRD - 1);
    for (int dz = -r; dz <= r; ++dz) {
      int z = cz + dz; if ((unsigned)z >= GRD) continue;
      for (int dy = -r; dy <= r; ++dy) {
        int y = cy + dy; if ((unsigned)y >= GRD) continue;
        int base = (z * GRD + y) * GRD;
        bool outer = (dy == -r || dy == r || dz == -r || dz == r);
        if (outer) {
          scan_range(cellstart[base + xl], cellstart[base + xh + 1]);
        } else {
          if (cx - r >= 0)  scan_range(cellstart[base + cx - r],
                                       cellstart[base + cx - r + 1]);
          if (cx + r < GRD) scan_range(cellstart[base + cx + r],
                                       cellstart[base + cx + r + 1]);
        }
      }
    }
    done = certify(r);
  }

  if (!done) {
    ovf[atomicAdd(ovf_cnt, 1)] = t;
    return;
  }

  float d0 = __uint_as_float((unsigned)(k0 >> 32));
  float d1 = __uint_as_float((unsigned)(k1 >> 32));
  float d2 = __uint_as_float((unsigned)(k2 >> 32));
  float w0 = 1.f / fmaxf(d0, EPS_W);
  float w1 = 1.f / fmaxf(d1, EPS_W);
  float w2 = 1.f / fmaxf(d2, EPS_W);
  float inv = 1.f / (w0 + w1 + w2);
  *(float4*)&widx[(size_t)t * 8] = make_float4(w0 * inv, w1 * inv, w2 * inv, 0.f);
  *(float4*)&widx[(size_t)t * 8 + 4] =
      make_float4(__uint_as_float((unsigned)k0), __uint_as_float((unsigned)k1),
                  __uint_as_float((unsigned)k2), 0.f);
}

// ---------------------------------------------------------------------------
// Brute fallback: 4 targets/block (one per wave), sources staged through LDS
// in 1024-point tiles (coalesced, latency amortized); wave-tree shfl merge
// (6 rounds x 3 key_inserts) replaces serial lane-0 merge. Exact u64 keys.
// ---------------------------------------------------------------------------
__global__ __launch_bounds__(256)
void knn_brute(const float* __restrict__ pos_t, const float4* __restrict__ plist,
               int Ns, const int* __restrict__ ovf_cnt,
               const int* __restrict__ ovf, float* __restrict__ widx)
{
  __shared__ float4 tile[1024];
  int n = *ovf_cnt;
  int ngrp = (n + 3) >> 2;                       // 4 targets per block
  int wv = threadIdx.x >> 6, ln = threadIdx.x & 63;

  for (int g = blockIdx.x; g < ngrp; g += gridDim.x) {
    int o = g * 4 + wv;
    bool active = (o < n);
    int t = active ? ovf[o] : 0;
    float tx = pos_t[3 * t], ty = pos_t[3 * t + 1], tz = pos_t[3 * t + 2];
    u64 k0 = ~0ULL, k1 = ~0ULL, k2 = ~0ULL;

    for (int base = 0; base < Ns; base += 1024) {
      int m = min(1024, Ns - base);
      __syncthreads();
      for (int i = threadIdx.x; i < m; i += 256) tile[i] = plist[base + i];
      __syncthreads();
#pragma unroll 4
      for (int p = ln; p < m; p += 64) {
        float4 s = tile[p];
        float dx = tx - s.x, dy = ty - s.y, dz = tz - s.z;
        float d = fmaf(dz, dz, fmaf(dy, dy, dx * dx));
        key_insert(((u64)__float_as_uint(d) << 32) | (u64)__float_as_uint(s.w),
                   k0, k1, k2);
      }
    }

    // wave tree-merge: after 6 rounds lane 0 holds the global top-3
#pragma unroll
    for (int off = 32; off >= 1; off >>= 1) {
      u64 a0 = __shfl_down(k0, off);
      u64 a1 = __shfl_down(k1, off);
      u64 a2 = __shfl_down(k2, off);
      key_insert(a0, k0, k1, k2);
      key_insert(a1, k0, k1, k2);
      key_insert(a2, k0, k1, k2);
    }

    if (active && ln == 0) {
      float d0 = __uint_as_float((unsigned)(k0 >> 32));
      float d1 = __uint_as_float((unsigned)(k1 >> 32));
      float d2 = __uint_as_float((unsigned)(k2 >> 32));
      float w0 = 1.f / fmaxf(d0, EPS_W);
      float w1 = 1.f / fmaxf(d1, EPS_W);
      float w2 = 1.f / fmaxf(d2, EPS_W);
      float inv = 1.f / (w0 + w1 + w2);
      *(float4*)&widx[(size_t)t * 8] =
          make_float4(w0 * inv, w1 * inv, w2 * inv, 0.f);
      *(float4*)&widx[(size_t)t * 8 + 4] =
          make_float4(__uint_as_float((unsigned)k0), __uint_as_float((unsigned)k1),
                      __uint_as_float((unsigned)k2), 0.f);
    }
  }
}

// ---------------------------------------------------------------------------
// fp32 tiled GEMM: Z[m][n] = sum_k A[m][k]*B[n][k] + bias[n]  (B = W row-major)
// CONCAT: A = [A0 (C0 cols) | A1]; BNIN: A = relu(bn(A0)).
// Epilogue: fused per-column sum/sumsq for the next BatchNorm.
// Block 256; tile BM x 64, BK=32. BM in {32, 64, 128}.
// ---------------------------------------------------------------------------
template<int BM, int CONCAT, int BNIN>
__global__ __launch_bounds__(256, 2)
void gemm_k(const float* __restrict__ A0, const float* __restrict__ A1, int C0,
            const float* __restrict__ B, const float* __restrict__ bias,
            const float* __restrict__ s_in, const float* __restrict__ q_in,
            const float* __restrict__ g_in, const float* __restrict__ be_in,
            float* __restrict__ Z, float* __restrict__ s_out, float* __restrict__ q_out,
            int M, int K, int N)
{
  const int BK = 32, BN = 64;
  const int AR = BM / 16;                    // rows per thread (2, 4 or 8)
  __shared__ float a_lds[BK][BM + 4];
  __shared__ float b_lds[BK][BN + 4];        // 2176 floats, reused as red
  __shared__ float bn_sc[256], bn_sh[256];

  const int tid = threadIdx.x;
  const int mb = blockIdx.x * BM;
  const int nb = blockIdx.y * BN;
  const int tn = tid & 15, tm = tid >> 4;

  if (BNIN) {
    for (int c = tid; c < K; c += 256) {
      float mean = s_in[c] / (float)M;
      float var  = q_in[c] / (float)M - mean * mean;
      float rstd = rsqrtf(var + EPS_BN);
      float sc = g_in[c] * rstd;
      bn_sc[c] = sc;
      bn_sh[c] = be_in[c] - mean * sc;
    }
    __syncthreads();
  }

  float acc[AR][4];
#pragma unroll
  for (int i = 0; i < AR; ++i)
#pragma unroll
    for (int j = 0; j < 4; ++j) acc[i][j] = 0.f;

  for (int kb = 0; kb < K; kb += BK) {
    const float* Ap; int ldA, ko;
    if (CONCAT) {
      if (kb < C0) { Ap = A0; ldA = C0;     ko = kb; }
      else         { Ap = A1; ldA = K - C0; ko = kb - C0; }
    } else { Ap = A0; ldA = K; ko = kb; }

#pragma unroll
    for (int sl = tid; sl < BM * 8; sl += 256) {
      int m = sl >> 3, k4 = (sl & 7) * 4;
      float4 v = *(const float4*)(Ap + (size_t)(mb + m) * ldA + ko + k4);
      if (BNIN) {
        v.x = fmaxf(v.x * bn_sc[kb + k4 + 0] + bn_sh[kb + k4 + 0], 0.f);
        v.y = fmaxf(v.y * bn_sc[kb + k4 + 1] + bn_sh[kb + k4 + 1], 0.f);
        v.z = fmaxf(v.z * bn_sc[kb + k4 + 2] + bn_sh[kb + k4 + 2], 0.f);
        v.w = fmaxf(v.w * bn_sc[kb + k4 + 3] + bn_sh[kb + k4 + 3], 0.f);
      }
      a_lds[k4 + 0][m] = v.x; a_lds[k4 + 1][m] = v.y;
      a_lds[k4 + 2][m] = v.z; a_lds[k4 + 3][m] = v.w;
    }
#pragma unroll
    for (int sl = tid; sl < 512; sl += 256) {
      int n = sl >> 3, k4 = (sl & 7) * 4;
      float4 v = *(const float4*)(B + (size_t)(nb + n) * K + kb + k4);
      b_lds[k4 + 0][n] = v.x; b_lds[k4 + 1][n] = v.y;
      b_lds[k4 + 2][n] = v.z; b_lds[k4 + 3][n] = v.w;
    }
    __syncthreads();

#pragma unroll
    for (int k = 0; k < BK; ++k) {
      float4 bv = *(const float4*)&b_lds[k][tn * 4];
      float av[AR];
      if (BM == 32) {
        av[0] = a_lds[k][tm * 2 + 0];
        av[1] = a_lds[k][tm * 2 + 1];
      } else {
        float4 a0 = *(const float4*)&a_lds[k][tm * 4];
        av[0] = a0.x; av[1] = a0.y; av[2] = a0.z; av[3] = a0.w;
        if (BM == 128) {
          float4 a1 = *(const float4*)&a_lds[k][tm * 4 + 64];
          av[4] = a1.x; av[5] = a1.y; av[6] = a1.z; av[7] = a1.w;
        }
      }
#pragma unroll
      for (int i = 0; i < AR; ++i) {
        acc[i][0] += av[i] * bv.x;
        acc[i][1] += av[i] * bv.y;
        acc[i][2] += av[i] * bv.z;
        acc[i][3] += av[i] * bv.w;
      }
    }
    __syncthreads();
  }

  // epilogue: bias add, store, per-column partial stats
  float4 bb = *(const float4*)&bias[nb + tn * 4];
  float psum[4] = {0, 0, 0, 0}, psq[4] = {0, 0, 0, 0};
#pragma unroll
  for (int i = 0; i < AR; ++i) {
    int m = (BM == 128) ? (tm * 4 + (i & 3) + ((i >= 4) ? 64 : 0))
                        : (tm * AR + i);
    float4 v;
    v.x = acc[i][0] + bb.x; v.y = acc[i][1] + bb.y;
    v.z = acc[i][2] + bb.z; v.w = acc[i][3] + bb.w;
    *(float4*)(Z + (size_t)(mb + m) * N + nb + tn * 4) = v;
    psum[0] += v.x; psum[1] += v.y; psum[2] += v.z; psum[3] += v.w;
    psq[0] += v.x * v.x; psq[1] += v.y * v.y;
    psq[2] += v.z * v.z; psq[3] += v.w * v.w;
  }
  __syncthreads();
  float* red = &b_lds[0][0];                 // 2176 floats >= 2048
  int base = tm * 64 + tn * 4;
#pragma unroll
  for (int j = 0; j < 4; ++j) {
    red[base + j] = psum[j];
    red[1024 + base + j] = psq[j];
  }
  __syncthreads();
  if (tid < 64) {
    float s = 0.f, q = 0.f;
#pragma unroll
    for (int it = 0; it < 16; ++it) {
      s += red[it * 64 + tid];
      q += red[1024 + it * 64 + tid];
    }
    atomicAdd(&s_out[nb + tid], s);
    atomicAdd(&q_out[nb + tid], q);
  }
}

// ---------------------------------------------------------------------------
// Final elementwise per level: out = relu(bn1(z1)) + relu(bn2(z2))
// ---------------------------------------------------------------------------
__global__ __launch_bounds__(256)
void final_k(const float* __restrict__ z1, const float* __restrict__ z2,
             const float* __restrict__ s1, const float* __restrict__ q1,
             const float* __restrict__ g1, const float* __restrict__ be1,
             const float* __restrict__ s2, const float* __restrict__ q2,
             const float* __restrict__ g2, const float* __restrict__ be2,
             float* __restrict__ outp, int M, int C)
{
  __shared__ float sc1[256], sh1[256], sc2[256], sh2[256];
  for (int c = threadIdx.x; c < C; c += 256) {
    float mean = s1[c] / (float)M;
    float var  = q1[c] / (float)M - mean * mean;
    float r = rsqrtf(var + EPS_BN);
    sc1[c] = g1[c] * r; sh1[c] = be1[c] - mean * sc1[c];
    mean = s2[c] / (float)M;
    var  = q2[c] / (float)M - mean * mean;
    r = rsqrtf(var + EPS_BN);
    sc2[c] = g2[c] * r; sh2[c] = be2[c] - mean * sc2[c];
  }
  __syncthreads();

  int total4 = M * C / 4;
  int cmask = (C / 4) - 1;                   // C/4 is a power of two
  for (int i = blockIdx.x * 256 + threadIdx.x; i < total4; i += gridDim.x * 256) {
    int c = (i & cmask) * 4;
    float4 a = ((const float4*)z1)[i];
    float4 b = ((const float4*)z2)[i];
    float4 r;
    r.x = fmaxf(a.x * sc1[c + 0] + sh1[c + 0], 0.f) + fmaxf(b.x * sc2[c + 0] + sh2[c + 0], 0.f);
    r.y = fmaxf(a.y * sc1[c + 1] + sh1[c + 1], 0.f) + fmaxf(b.y * sc2[c + 1] + sh2[c + 1], 0.f);
    r.z = fmaxf(a.z * sc1[c + 2] + sh1[c + 2], 0.f) + fmaxf(b.z * sc2[c + 2] + sh2[c + 2], 0.f);
    r.w = fmaxf(a.w * sc1[c + 3] + sh1[c + 3], 0.f) + fmaxf(b.w * sc2[c + 3] + sh2[c + 3], 0.f);
    ((float4*)outp)[i] = r;
  }
}

// ---------------------------------------------------------------------------
extern "C" void kernel_launch(void* const* d_in, const int* in_sizes, int n_in,
                              void* d_out, int out_size, void* d_ws, size_t ws_size,
                              hipStream_t stream)
{
  const bool dict_order = (in_sizes[1] == 512 * 512);

  const float* POS[4];
  const float* X[4];
  for (int i = 0; i < 4; ++i) {
    POS[i] = (const float*)d_in[dict_order ? 3 * i : i];
    X[i]   = (const float*)d_in[dict_order ? 3 * i + 1 : 4 + i];
  }
  static const int dict_map[8] = {0, 2, 6, 3, 1, 4, 7, 5};
  auto PRM = [&](int lvl, int which) -> const float* {
    int idx = dict_order ? (12 + 8 * lvl + dict_map[which]) : (8 + 8 * lvl + which);
    return (const float*)d_in[idx];
  };

  // Workspace layout. cd/ci alias z1/z2 (L0/L1 path); L2 grid scratch also
  // lives in the z1 region (dead before L2 gemm1 writes z1; only widx, which
  // lives outside, survives). Stream order serializes all hazards.
  char* ws = (char*)d_ws;
  float* up    = (float*)(ws);                          // 16 MB max (L2)
  float* z1    = (float*)(ws + (16u << 20));            // 8 MB max
  float* z2    = (float*)(ws + (24u << 20));            // 8 MB max
  float* cd    = z1;
  int*   ci    = (int*)z2;
  float* x1o   = (float*)(ws + (32u << 20));            // 2 MB
  float* x2o   = (float*)(ws + (34u << 20));            // 4 MB
  float* stats = (float*)(ws + (38u << 20));            // 4 KB (pad 8 KB)
  float* s1 = stats, *q1 = stats + 256, *s2 = stats + 512, *q2 = stats + 768;
  float* widx  = (float*)(ws + (38u << 20) + 8192);     // 1 MB

  // grid scratch inside z1 region (<= 5.2 MB of 8 MB)
  char* gb = ws + (16u << 20);
  const size_t S = 600 * 1024;
  int*    cnt      = (int*)(gb + 0 * S);
  int*    tcnt     = (int*)(gb + 1 * S);
  int*    ofsp     = (int*)(gb + 2 * S);
  int*    tofsp    = (int*)(gb + 3 * S);
  int*    cursor   = (int*)(gb + 4 * S);
  int*    tcursor  = (int*)(gb + 5 * S);
  int*    cellstart= (int*)(gb + 6 * S);                // NCELLS+1 ints
  char*   gb2      = gb + 7 * S;
  int*    aux      = (int*)(gb2);
  int*    auxp     = (int*)(gb2 + 1024);
  int*    aux2     = (int*)(gb2 + 2048);
  int*    auxp2    = (int*)(gb2 + 3072);
  int*    pcell    = (int*)(gb2 + 4096);                        // 32 KB
  int*    tpcell   = (int*)(gb2 + 4096 + 32768);                // 128 KB
  float4* plist    = (float4*)(gb2 + 4096 + 32768 + 131072);    // 128 KB
  int*    tsorted  = (int*)(gb2 + 4096 + 32768 + 2 * 131072);   // 128 KB
  int*    ovfc     = (int*)(gb2 + 4096 + 32768 + 3 * 131072);
  int*    ovf      = (int*)(gb2 + 4096 + 32768 + 3 * 131072 + 1024); // 128 KB

  // ======================= Level 0: 512 -> 2048 ============================
  knn_part<1><<<dim3(8, 16), 256, 0, stream>>>(POS[0], POS[1], 512, 2048, 16, cd, ci);
  merge_gather<512, 0><<<32, 256, 0, stream>>>(cd, ci, 16, X[0], up, 2048, stats, nullptr);
  gemm_k<32, 1, 0><<<dim3(64, 4), 256, 0, stream>>>(
      X[1], up, 256, PRM(0, 0), PRM(0, 1),
      nullptr, nullptr, nullptr, nullptr,
      z1, s1, q1, 2048, 768, 256);
  gemm_k<32, 0, 1><<<dim3(64, 4), 256, 0, stream>>>(
      z1, nullptr, 0, PRM(0, 4), PRM(0, 5),
      s1, q1, PRM(0, 2), PRM(0, 3),
      z2, s2, q2, 2048, 256, 256);
  final_k<<<512, 256, 0, stream>>>(z1, z2, s1, q1, PRM(0, 2), PRM(0, 3),
                                   s2, q2, PRM(0, 6), PRM(0, 7), x1o, 2048, 256);

  // ======================= Level 1: 2048 -> 8192 ===========================
  knn_part<1><<<dim3(32, 32), 256, 0, stream>>>(POS[1], POS[2], 2048, 8192, 32, cd, ci);
  merge_gather<256, 0><<<128, 256, 0, stream>>>(cd, ci, 32, x1o, up, 8192, stats, nullptr);
  gemm_k<64, 1, 0><<<dim3(128, 2), 256, 0, stream>>>(
      X[2], up, 128, PRM(1, 0), PRM(1, 1),
      nullptr, nullptr, nullptr, nullptr,
      z1, s1, q1, 8192, 384, 128);
  gemm_k<64, 0, 1><<<dim3(128, 2), 256, 0, stream>>>(
      z1, nullptr, 0, PRM(1, 4), PRM(1, 5),
      s1, q1, PRM(1, 2), PRM(1, 3),
      z2, s2, q2, 8192, 128, 128);
  final_k<<<1024, 256, 0, stream>>>(z1, z2, s1, q1, PRM(1, 2), PRM(1, 3),
                                    s2, q2, PRM(1, 6), PRM(1, 7), x2o, 8192, 128);

  // ======================= Level 2: 8192 -> 32768 (grid KNN) ===============
  hipMemsetAsync(cnt, 0, 2 * S, stream);                 // cnt + tcnt
  grid_count2<<<dim3(128, 2), 256, 0, stream>>>(POS[2], 8192, cnt, pcell,
                                                POS[3], 32768, tcnt, tpcell);
  grid_scan1<<<dim3(138, 2), 256, 0, stream>>>(cnt, ofsp, aux, tcnt, tofsp, aux2);
  grid_scan2<<<2, 256, 0, stream>>>(aux, auxp, aux2, auxp2, 138);
  grid_fixup2<<<dim3(256, 2), 256, 0, stream>>>(ofsp, auxp, cursor, cellstart, 8192,
                                                tofsp, auxp2, tcursor, ovfc);
  grid_scatter2<<<dim3(128, 2), 256, 0, stream>>>(POS[2], 8192, pcell, cursor, plist,
                                                  32768, tpcell, tcursor, tsorted);
  knn_search27<<<128, 256, 0, stream>>>(POS[3], 32768, cellstart, plist,
                                        tsorted, widx, ovfc, ovf);
  knn_brute<<<128, 256, 0, stream>>>(POS[3], plist, 8192, ovfc, ovf, widx);
  merge_gather<128, 1><<<512, 256, 0, stream>>>(nullptr, nullptr, 0, x2o, up,
                                                32768, stats, widx);
  gemm_k<64, 1, 0><<<dim3(512, 1), 256, 0, stream>>>(
      X[3], up, 64, PRM(2, 0), PRM(2, 1),
      nullptr, nullptr, nullptr, nullptr,
      z1, s1, q1, 32768, 192, 64);
  gemm_k<64, 0, 1><<<dim3(512, 1), 256, 0, stream>>>(
      z1, nullptr, 0, PRM(2, 4), PRM(2, 5),
      s1, q1, PRM(2, 2), PRM(2, 3),
      z2, s2, q2, 32768, 64, 64);
  final_k<<<1024, 256, 0, stream>>>(z1, z2, s1, q1, PRM(2, 2), PRM(2, 3),
                                    s2, q2, PRM(2, 6), PRM(2, 7),
                                    (float*)d_out, 32768, 64);
}

// Round 7
// 453.416 us; speedup vs baseline: 1.2922x; 1.2922x over previous
//
#include <hip/hip_runtime.h>

// PointNet++-style decoder forward: 3 levels of {knn_interpolate -> concat ->
// Lin+BN+ReLU -> residual Lin+BN+ReLU}. All fp32. Single batch.

#define EPS_BN 1e-5f
#define EPS_W  1e-16f

// ---- L2 KNN spatial grid parameters (sources = 8192 Gaussian pts) ---------
#define GRD    52
#define GLO   -6.5f
#define GH     0.25f
#define GIH    4.0f
#define NCELLS (GRD * GRD * GRD)   // 140608

typedef unsigned long long u64;

// ---------------------------------------------------------------------------
// Brute KNN pass 1 (levels 0,1): split over sources. Block = 256 threads x
// TPT targets vs one source chunk in LDS. Branchless sorted top-3.
// ---------------------------------------------------------------------------
template<int TPT>
__global__ __launch_bounds__(256)
void knn_part(const float* __restrict__ pos_s, const float* __restrict__ pos_t,
              int Ns, int Nt, int nsplit,
              float* __restrict__ cand_d, int* __restrict__ cand_i)
{
  __shared__ float4 sp[512];

  const int tb  = blockIdx.x;
  const int spl = blockIdx.y;
  const int chunk = Ns / nsplit;
  const int cs = spl * chunk;

  float tx[TPT], ty[TPT], tz[TPT];
  float d0[TPT], d1[TPT], d2[TPT];
  int   j0[TPT], j1[TPT], j2[TPT];

#pragma unroll
  for (int q = 0; q < TPT; ++q) {
    int t = tb * 256 * TPT + q * 256 + threadIdx.x;
    tx[q] = pos_t[3 * t + 0];
    ty[q] = pos_t[3 * t + 1];
    tz[q] = pos_t[3 * t + 2];
    d0[q] = 3.4e38f; d1[q] = 3.4e38f; d2[q] = 3.4e38f;
    j0[q] = 0; j1[q] = 0; j2[q] = 0;
  }

  for (int i = threadIdx.x; i < chunk; i += 256) {
    int p = cs + i;
    sp[i] = make_float4(pos_s[3 * p], pos_s[3 * p + 1], pos_s[3 * p + 2], 0.f);
  }
  __syncthreads();

#pragma unroll 4
  for (int j = 0; j < chunk; ++j) {
    float4 s = sp[j];
    int gj = cs + j;
#pragma unroll
    for (int q = 0; q < TPT; ++q) {
      float dx = tx[q] - s.x, dy = ty[q] - s.y, dz = tz[q] - s.z;
      float nd = fmaf(dz, dz, fmaf(dy, dy, dx * dx));
      int nj = gj;
      bool c = nd < d0[q];
      float td = c ? d0[q] : nd;  int tj = c ? j0[q] : nj;
      d0[q] = c ? nd : d0[q];     j0[q] = c ? nj : j0[q];
      nd = td; nj = tj;
      c = nd < d1[q];
      td = c ? d1[q] : nd;        tj = c ? j1[q] : nj;
      d1[q] = c ? nd : d1[q];     j1[q] = c ? nj : j1[q];
      nd = td; nj = tj;
      c = nd < d2[q];
      d2[q] = c ? nd : d2[q];     j2[q] = c ? nj : j2[q];
    }
  }

#pragma unroll
  for (int q = 0; q < TPT; ++q) {
    int t = tb * 256 * TPT + q * 256 + threadIdx.x;
    int o = (t * nsplit + spl) * 3;
    cand_d[o + 0] = d0[q]; cand_d[o + 1] = d1[q]; cand_d[o + 2] = d2[q];
    cand_i[o + 0] = j0[q]; cand_i[o + 1] = j1[q]; cand_i[o + 2] = j2[q];
  }
}

// ---------------------------------------------------------------------------
// Merge + gather (all levels): block = 64 targets x 4 channel-groups.
// FROMW=0: merge nsplit partial top-3 lists; FROMW=1: read widx (L2 path).
// Block 0 zeroes the BN stats accumulators for the following GEMMs.
// ---------------------------------------------------------------------------
template<int CS, int FROMW>
__global__ __launch_bounds__(256)
void merge_gather(const float* __restrict__ cand_d, const int* __restrict__ cand_i,
                  int nsplit, const float* __restrict__ xs,
                  float* __restrict__ up, int Nt,
                  float* __restrict__ stats0, const float* __restrict__ widx)
{
  if (blockIdx.x == 0) {
    for (int i = threadIdx.x; i < 1024; i += 256) stats0[i] = 0.f;
  }

  int t  = blockIdx.x * 64 + (threadIdx.x >> 2);
  int cg = threadIdx.x & 3;

  float w0, w1, w2; int i0, i1, i2;
  if (FROMW) {
    float4 wv = *(const float4*)&widx[(size_t)t * 8];
    float4 iv = *(const float4*)&widx[(size_t)t * 8 + 4];
    w0 = wv.x; w1 = wv.y; w2 = wv.z;
    i0 = (int)__float_as_uint(iv.x);
    i1 = (int)__float_as_uint(iv.y);
    i2 = (int)__float_as_uint(iv.z);
  } else {
    float e0 = 3.5e38f, e1 = 3.5e38f, e2 = 3.5e38f;
    i0 = 0; i1 = 0; i2 = 0;
    int o = t * nsplit * 3;
    for (int c = 0; c < nsplit * 3; ++c) {
      float d = cand_d[o + c];
      int   i = cand_i[o + c];
      if (d < e2) {
        if (d < e1) {
          e2 = e1; i2 = i1;
          if (d < e0) { e1 = e0; i1 = i0; e0 = d; i0 = i; }
          else        { e1 = d;  i1 = i; }
        } else { e2 = d; i2 = i; }
      }
    }
    w0 = 1.f / fmaxf(e0, EPS_W);
    w1 = 1.f / fmaxf(e1, EPS_W);
    w2 = 1.f / fmaxf(e2, EPS_W);
    float inv = 1.f / (w0 + w1 + w2);
    w0 *= inv; w1 *= inv; w2 *= inv;
  }

  const float4* r0 = (const float4*)(xs + (size_t)i0 * CS);
  const float4* r1 = (const float4*)(xs + (size_t)i1 * CS);
  const float4* r2 = (const float4*)(xs + (size_t)i2 * CS);
  float4* ou = (float4*)(up + (size_t)t * CS);
  const int F4 = CS / 4;
#pragma unroll 4
  for (int k = 0; k < F4 / 4; ++k) {
    int f = cg + 4 * k;
    float4 a = r0[f], b = r1[f], d = r2[f], rr;
    rr.x = w0 * a.x + w1 * b.x + w2 * d.x;
    rr.y = w0 * a.y + w1 * b.y + w2 * d.y;
    rr.z = w0 * a.z + w1 * b.z + w2 * d.z;
    rr.w = w0 * a.w + w1 * b.w + w2 * d.w;
    ou[f] = rr;
  }
}

// ---------------------------------------------------------------------------
// Grid build (L2). Fused source/target variants via blockIdx.y.
// ---------------------------------------------------------------------------
__device__ __forceinline__ int cell_coord(float v) {
  return min(max((int)floorf((v - GLO) * GIH), 0), GRD - 1);
}

__global__ __launch_bounds__(256)
void grid_count2(const float* __restrict__ ps, int ns, int* __restrict__ cnt,
                 int* __restrict__ pcell,
                 const float* __restrict__ pt, int nt, int* __restrict__ tcnt,
                 int* __restrict__ tpcell)
{
  int i = blockIdx.x * 256 + threadIdx.x;
  const float* p; int n; int* c; int* pc;
  if (blockIdx.y == 0) { p = ps; n = ns; c = cnt;  pc = pcell; }
  else                 { p = pt; n = nt; c = tcnt; pc = tpcell; }
  if (i >= n) return;
  int cx = cell_coord(p[3 * i + 0]);
  int cy = cell_coord(p[3 * i + 1]);
  int cz = cell_coord(p[3 * i + 2]);
  int cid = (cz * GRD + cy) * GRD + cx;
  pc[i] = cid;
  atomicAdd(&c[cid], 1);
}

__global__ __launch_bounds__(256)
void grid_scan1(const int* __restrict__ cntA, int* __restrict__ ofspA,
                int* __restrict__ auxA,
                const int* __restrict__ cntB, int* __restrict__ ofspB,
                int* __restrict__ auxB)
{
  const int* cnt; int* ofsp; int* aux;
  if (blockIdx.y == 0) { cnt = cntA; ofsp = ofspA; aux = auxA; }
  else                 { cnt = cntB; ofsp = ofspB; aux = auxB; }
  __shared__ int arr[256];
  int tid = threadIdx.x;
  int c0 = blockIdx.x * 1024 + tid * 4;
  int s0 = (c0 + 0 < NCELLS) ? cnt[c0 + 0] : 0;
  int s1 = (c0 + 1 < NCELLS) ? cnt[c0 + 1] : 0;
  int s2 = (c0 + 2 < NCELLS) ? cnt[c0 + 2] : 0;
  int s3 = (c0 + 3 < NCELLS) ? cnt[c0 + 3] : 0;
  int p1 = s0, p2 = s0 + s1, p3 = p2 + s2, tot = p3 + s3;
  arr[tid] = tot; __syncthreads();
  for (int d = 1; d < 256; d <<= 1) {
    int v = (tid >= d) ? arr[tid - d] : 0;
    __syncthreads();
    arr[tid] += v;
    __syncthreads();
  }
  int excl = arr[tid] - tot;
  if (c0 + 0 < NCELLS) ofsp[c0 + 0] = excl;
  if (c0 + 1 < NCELLS) ofsp[c0 + 1] = excl + p1;
  if (c0 + 2 < NCELLS) ofsp[c0 + 2] = excl + p2;
  if (c0 + 3 < NCELLS) ofsp[c0 + 3] = excl + p3;
  if (tid == 255) aux[blockIdx.x] = arr[255];
}

__global__ __launch_bounds__(256)
void grid_scan2(const int* __restrict__ auxA, int* __restrict__ auxpA,
                const int* __restrict__ auxB, int* __restrict__ auxpB, int nblk)
{
  const int* aux; int* auxp;
  if (blockIdx.x == 0) { aux = auxA; auxp = auxpA; }
  else                 { aux = auxB; auxp = auxpB; }
  __shared__ int arr[256];
  int tid = threadIdx.x;
  int v = (tid < nblk) ? aux[tid] : 0;
  arr[tid] = v; __syncthreads();
  for (int d = 1; d < 256; d <<= 1) {
    int w = (tid >= d) ? arr[tid - d] : 0;
    __syncthreads();
    arr[tid] += w;
    __syncthreads();
  }
  auxp[tid] = arr[tid] - v;   // exclusive
}

// side 0: cursor + cellstart (+sentinel, ovfc=0); side 1: tcursor only.
__global__ __launch_bounds__(256)
void grid_fixup2(const int* __restrict__ ofsp, const int* __restrict__ auxp,
                 int* __restrict__ cursor, int* __restrict__ cellstart,
                 int ns_total,
                 const int* __restrict__ tofsp, const int* __restrict__ tauxp,
                 int* __restrict__ tcursor, int* __restrict__ ovf_cnt)
{
  int i = blockIdx.x * 256 + threadIdx.x;
  if (blockIdx.y == 0) {
    if (i == 0) { *ovf_cnt = 0; cellstart[NCELLS] = ns_total; }
    for (int c = i; c < NCELLS; c += gridDim.x * 256) {
      int v = ofsp[c] + auxp[c >> 10];
      cursor[c] = v;
      cellstart[c] = v;
    }
  } else {
    for (int c = i; c < NCELLS; c += gridDim.x * 256)
      tcursor[c] = tofsp[c] + tauxp[c >> 10];
  }
}

// side 0: scatter source points as float4(pos,idx); side 1: target index sort.
__global__ __launch_bounds__(256)
void grid_scatter2(const float* __restrict__ ps, int ns,
                   const int* __restrict__ pcell, int* __restrict__ cursor,
                   float4* __restrict__ plist,
                   int nt, const int* __restrict__ tpcell,
                   int* __restrict__ tcursor, int* __restrict__ tsorted)
{
  int i = blockIdx.x * 256 + threadIdx.x;
  if (blockIdx.y == 0) {
    if (i >= ns) return;
    int slot = atomicAdd(&cursor[pcell[i]], 1);
    plist[slot] = make_float4(ps[3 * i], ps[3 * i + 1], ps[3 * i + 2],
                              __uint_as_float((unsigned)i));
  } else {
    if (i >= nt) return;
    int slot = atomicAdd(&tcursor[tpcell[i]], 1);
    tsorted[slot] = i;
  }
}

// ---------------------------------------------------------------------------
// L2 KNN search, quad-per-target: 4 lanes share one target; phase-1 rows
// (9 contiguous x-row ranges) and phase-2 ranges (34) are split across the
// quad and merged with a 2-round shfl_xor butterfly. Sets merged are always
// DISJOINT (phase-2 uses fresh keys, then one cross-set merge) so no
// duplicate-key corruption. u64 keys (dist<<32|idx): scatter-order
// independent, ties by smaller index (jax.lax.top_k stability). Certify via
// exact cube-face lower bound at r=1,2; else overflow -> exact brute.
// Cell-sorted target order keeps waves spatially coherent.
// ---------------------------------------------------------------------------
__device__ __forceinline__ void key_insert(u64 nk, u64& k0, u64& k1, u64& k2) {
  bool c = nk < k0; u64 tk = c ? k0 : nk; k0 = c ? nk : k0; nk = tk;
  c = nk < k1; tk = c ? k1 : nk; k1 = c ? nk : k1; nk = tk;
  c = nk < k2; k2 = c ? nk : k2;
}

__device__ __forceinline__ void quad_merge(u64& k0, u64& k1, u64& k2) {
#pragma unroll
  for (int off = 1; off <= 2; off <<= 1) {
    u64 a0 = __shfl_xor(k0, off);
    u64 a1 = __shfl_xor(k1, off);
    u64 a2 = __shfl_xor(k2, off);
    key_insert(a0, k0, k1, k2);
    key_insert(a1, k0, k1, k2);
    key_insert(a2, k0, k1, k2);
  }
}

__global__ __launch_bounds__(256)
void knn_search_quad(const float* __restrict__ pos_t, int Nt,
                     const int* __restrict__ cellstart,
                     const float4* __restrict__ plist,
                     const int* __restrict__ tsorted,
                     float* __restrict__ widx,
                     int* __restrict__ ovf_cnt, int* __restrict__ ovf)
{
  int gid = blockIdx.x * 64 + (threadIdx.x >> 2);   // 64 targets per block
  int sub = threadIdx.x & 3;
  if (gid >= Nt) return;
  int t = tsorted[gid];
  float tx = pos_t[3 * t], ty = pos_t[3 * t + 1], tz = pos_t[3 * t + 2];
  int cx = cell_coord(tx), cy = cell_coord(ty), cz = cell_coord(tz);

  u64 k0 = ~0ULL, k1 = ~0ULL, k2 = ~0ULL;

  auto scan_range = [&](int p0, int p1, u64& a0, u64& a1, u64& a2) {
    for (int p = p0; p < p1; ++p) {
      float4 s = plist[p];
      float dx = tx - s.x, dy = ty - s.y, dz = tz - s.z;
      float d = fmaf(dz, dz, fmaf(dy, dy, dx * dx));
      key_insert(((u64)__float_as_uint(d) << 32) | (u64)__float_as_uint(s.w),
                 a0, a1, a2);
    }
  };

  auto certify = [&](int R) -> bool {
    int xl = max(cx - R, 0), xh = min(cx + R, GRD - 1);
    int yl = max(cy - R, 0), yh = min(cy + R, GRD - 1);
    int zl = max(cz - R, 0), zh = min(cz + R, GRD - 1);
    float m = 1e30f;
    if (xl > 0)       m = fminf(m, tx - (GLO + xl * GH));
    if (xh < GRD - 1) m = fminf(m, (GLO + (xh + 1) * GH) - tx);
    if (yl > 0)       m = fminf(m, ty - (GLO + yl * GH));
    if (yh < GRD - 1) m = fminf(m, (GLO + (yh + 1) * GH) - ty);
    if (zl > 0)       m = fminf(m, tz - (GLO + zl * GH));
    if (zh < GRD - 1) m = fminf(m, (GLO + (zh + 1) * GH) - tz);
    float d2b = __uint_as_float((unsigned)(k2 >> 32));   // NaN if <3 found
    return (m * m * 0.9999f > d2b);                      // NaN -> false
  };

  // Phase 1: 9 rows split across the quad (lane sub: rows sub, sub+4, sub+8)
  int xlo = max(cx - 1, 0), xhi = min(cx + 1, GRD - 1);
  for (int id = sub; id < 9; id += 4) {
    int y = cy + (id % 3) - 1, z = cz + (id / 3) - 1;
    if (((unsigned)y < GRD) && ((unsigned)z < GRD)) {
      int base = (z * GRD + y) * GRD;
      scan_range(cellstart[base + xlo], cellstart[base + xhi + 1], k0, k1, k2);
    }
  }
  quad_merge(k0, k1, k2);          // disjoint partials -> all lanes hold top-3
  bool done = certify(1);

  if (!done) {
    // Phase 2: r=2 shell as 34 ranges: 16 outer rows (full x span) +
    // 9 inner rows x 2 caps. Fresh keys per lane (disjoint), butterfly,
    // then one cross-set merge into the shared phase-1 keys.
    static const signed char o_dy[16] = {-2,-1,0,1,2, -2,-1,0,1,2, -2,-2,-2, 2,2,2};
    static const signed char o_dz[16] = {-2,-2,-2,-2,-2, 2,2,2,2,2, -1,0,1, -1,0,1};
    int xl2 = max(cx - 2, 0), xh2 = min(cx + 2, GRD - 1);
    u64 p0 = ~0ULL, p1 = ~0ULL, p2 = ~0ULL;
    for (int id = sub; id < 34; id += 4) {
      if (id < 16) {
        int y = cy + o_dy[id], z = cz + o_dz[id];
        if (((unsigned)y < GRD) && ((unsigned)z < GRD)) {
          int base = (z * GRD + y) * GRD;
          scan_range(cellstart[base + xl2], cellstart[base + xh2 + 1], p0, p1, p2);
        }
      } else {
        int row = (id - 16) >> 1, side = (id - 16) & 1;
        int y = cy + (row % 3) - 1, z = cz + (row / 3) - 1;
        int x = side ? (cx + 2) : (cx - 2);
        if (((unsigned)y < GRD) && ((unsigned)z < GRD) && ((unsigned)x < GRD)) {
          int base = (z * GRD + y) * GRD;
          scan_range(cellstart[base + x], cellstart[base + x + 1], p0, p1, p2);
        }
      }
    }
    quad_merge(p0, p1, p2);
    key_insert(p0, k0, k1, k2);    // phase-2 set disjoint from phase-1 set
    key_insert(p1, k0, k1, k2);
    key_insert(p2, k0, k1, k2);
    done = certify(2);
  }

  if (!done) {
    if (sub == 0) ovf[atomicAdd(ovf_cnt, 1)] = t;
    return;
  }

  if (sub == 0) {
    float d0 = __uint_as_float((unsigned)(k0 >> 32));
    float d1 = __uint_as_float((unsigned)(k1 >> 32));
    float d2 = __uint_as_float((unsigned)(k2 >> 32));
    float w0 = 1.f / fmaxf(d0, EPS_W);
    float w1 = 1.f / fmaxf(d1, EPS_W);
    float w2 = 1.f / fmaxf(d2, EPS_W);
    float inv = 1.f / (w0 + w1 + w2);
    *(float4*)&widx[(size_t)t * 8] =
        make_float4(w0 * inv, w1 * inv, w2 * inv, 0.f);
    *(float4*)&widx[(size_t)t * 8 + 4] =
        make_float4(__uint_as_float((unsigned)k0), __uint_as_float((unsigned)k1),
                    __uint_as_float((unsigned)k2), 0.f);
  }
}

// ---------------------------------------------------------------------------
// Brute fallback: 4 targets/block (one per wave), sources staged through LDS
// in 1024-point tiles (coalesced, latency amortized); wave-tree shfl merge
// (6 rounds x 3 key_inserts) replaces serial lane-0 merge. Exact u64 keys.
// ---------------------------------------------------------------------------
__global__ __launch_bounds__(256)
void knn_brute(const float* __restrict__ pos_t, const float4* __restrict__ plist,
               int Ns, const int* __restrict__ ovf_cnt,
               const int* __restrict__ ovf, float* __restrict__ widx)
{
  __shared__ float4 tile[1024];
  int n = *ovf_cnt;
  int ngrp = (n + 3) >> 2;                       // 4 targets per block
  int wv = threadIdx.x >> 6, ln = threadIdx.x & 63;

  for (int g = blockIdx.x; g < ngrp; g += gridDim.x) {
    int o = g * 4 + wv;
    bool active = (o < n);
    int t = active ? ovf[o] : 0;
    float tx = pos_t[3 * t], ty = pos_t[3 * t + 1], tz = pos_t[3 * t + 2];
    u64 k0 = ~0ULL, k1 = ~0ULL, k2 = ~0ULL;

    for (int base = 0; base < Ns; base += 1024) {
      int m = min(1024, Ns - base);
      __syncthreads();
      for (int i = threadIdx.x; i < m; i += 256) tile[i] = plist[base + i];
      __syncthreads();
#pragma unroll 4
      for (int p = ln; p < m; p += 64) {
        float4 s = tile[p];
        float dx = tx - s.x, dy = ty - s.y, dz = tz - s.z;
        float d = fmaf(dz, dz, fmaf(dy, dy, dx * dx));
        key_insert(((u64)__float_as_uint(d) << 32) | (u64)__float_as_uint(s.w),
                   k0, k1, k2);
      }
    }

    // wave tree-merge: after 6 rounds lane 0 holds the global top-3
#pragma unroll
    for (int off = 32; off >= 1; off >>= 1) {
      u64 a0 = __shfl_down(k0, off);
      u64 a1 = __shfl_down(k1, off);
      u64 a2 = __shfl_down(k2, off);
      key_insert(a0, k0, k1, k2);
      key_insert(a1, k0, k1, k2);
      key_insert(a2, k0, k1, k2);
    }

    if (active && ln == 0) {
      float d0 = __uint_as_float((unsigned)(k0 >> 32));
      float d1 = __uint_as_float((unsigned)(k1 >> 32));
      float d2 = __uint_as_float((unsigned)(k2 >> 32));
      float w0 = 1.f / fmaxf(d0, EPS_W);
      float w1 = 1.f / fmaxf(d1, EPS_W);
      float w2 = 1.f / fmaxf(d2, EPS_W);
      float inv = 1.f / (w0 + w1 + w2);
      *(float4*)&widx[(size_t)t * 8] =
          make_float4(w0 * inv, w1 * inv, w2 * inv, 0.f);
      *(float4*)&widx[(size_t)t * 8 + 4] =
          make_float4(__uint_as_float((unsigned)k0), __uint_as_float((unsigned)k1),
                      __uint_as_float((unsigned)k2), 0.f);
    }
  }
}

// ---------------------------------------------------------------------------
// fp32 tiled GEMM: Z[m][n] = sum_k A[m][k]*B[n][k] + bias[n]  (B = W row-major)
// CONCAT: A = [A0 (C0 cols) | A1]; BNIN: A = relu(bn(A0)).
// Epilogue: fused per-column sum/sumsq for the next BatchNorm.
// Block 256; tile BM x 64, BK=32. BM in {32, 64, 128}.
// ---------------------------------------------------------------------------
template<int BM, int CONCAT, int BNIN>
__global__ __launch_bounds__(256, 2)
void gemm_k(const float* __restrict__ A0, const float* __restrict__ A1, int C0,
            const float* __restrict__ B, const float* __restrict__ bias,
            const float* __restrict__ s_in, const float* __restrict__ q_in,
            const float* __restrict__ g_in, const float* __restrict__ be_in,
            float* __restrict__ Z, float* __restrict__ s_out, float* __restrict__ q_out,
            int M, int K, int N)
{
  const int BK = 32, BN = 64;
  const int AR = BM / 16;                    // rows per thread (2, 4 or 8)
  __shared__ float a_lds[BK][BM + 4];
  __shared__ float b_lds[BK][BN + 4];        // 2176 floats, reused as red
  __shared__ float bn_sc[256], bn_sh[256];

  const int tid = threadIdx.x;
  const int mb = blockIdx.x * BM;
  const int nb = blockIdx.y * BN;
  const int tn = tid & 15, tm = tid >> 4;

  if (BNIN) {
    for (int c = tid; c < K; c += 256) {
      float mean = s_in[c] / (float)M;
      float var  = q_in[c] / (float)M - mean * mean;
      float rstd = rsqrtf(var + EPS_BN);
      float sc = g_in[c] * rstd;
      bn_sc[c] = sc;
      bn_sh[c] = be_in[c] - mean * sc;
    }
    __syncthreads();
  }

  float acc[AR][4];
#pragma unroll
  for (int i = 0; i < AR; ++i)
#pragma unroll
    for (int j = 0; j < 4; ++j) acc[i][j] = 0.f;

  for (int kb = 0; kb < K; kb += BK) {
    const float* Ap; int ldA, ko;
    if (CONCAT) {
      if (kb < C0) { Ap = A0; ldA = C0;     ko = kb; }
      else         { Ap = A1; ldA = K - C0; ko = kb - C0; }
    } else { Ap = A0; ldA = K; ko = kb; }

#pragma unroll
    for (int sl = tid; sl < BM * 8; sl += 256) {
      int m = sl >> 3, k4 = (sl & 7) * 4;
      float4 v = *(const float4*)(Ap + (size_t)(mb + m) * ldA + ko + k4);
      if (BNIN) {
        v.x = fmaxf(v.x * bn_sc[kb + k4 + 0] + bn_sh[kb + k4 + 0], 0.f);
        v.y = fmaxf(v.y * bn_sc[kb + k4 + 1] + bn_sh[kb + k4 + 1], 0.f);
        v.z = fmaxf(v.z * bn_sc[kb + k4 + 2] + bn_sh[kb + k4 + 2], 0.f);
        v.w = fmaxf(v.w * bn_sc[kb + k4 + 3] + bn_sh[kb + k4 + 3], 0.f);
      }
      a_lds[k4 + 0][m] = v.x; a_lds[k4 + 1][m] = v.y;
      a_lds[k4 + 2][m] = v.z; a_lds[k4 + 3][m] = v.w;
    }
#pragma unroll
    for (int sl = tid; sl < 512; sl += 256) {
      int n = sl >> 3, k4 = (sl & 7) * 4;
      float4 v = *(const float4*)(B + (size_t)(nb + n) * K + kb + k4);
      b_lds[k4 + 0][n] = v.x; b_lds[k4 + 1][n] = v.y;
      b_lds[k4 + 2][n] = v.z; b_lds[k4 + 3][n] = v.w;
    }
    __syncthreads();

#pragma unroll
    for (int k = 0; k < BK; ++k) {
      float4 bv = *(const float4*)&b_lds[k][tn * 4];
      float av[AR];
      if (BM == 32) {
        av[0] = a_lds[k][tm * 2 + 0];
        av[1] = a_lds[k][tm * 2 + 1];
      } else {
        float4 a0 = *(const float4*)&a_lds[k][tm * 4];
        av[0] = a0.x; av[1] = a0.y; av[2] = a0.z; av[3] = a0.w;
        if (BM == 128) {
          float4 a1 = *(const float4*)&a_lds[k][tm * 4 + 64];
          av[4] = a1.x; av[5] = a1.y; av[6] = a1.z; av[7] = a1.w;
        }
      }
#pragma unroll
      for (int i = 0; i < AR; ++i) {
        acc[i][0] += av[i] * bv.x;
        acc[i][1] += av[i] * bv.y;
        acc[i][2] += av[i] * bv.z;
        acc[i][3] += av[i] * bv.w;
      }
    }
    __syncthreads();
  }

  // epilogue: bias add, store, per-column partial stats
  float4 bb = *(const float4*)&bias[nb + tn * 4];
  float psum[4] = {0, 0, 0, 0}, psq[4] = {0, 0, 0, 0};
#pragma unroll
  for (int i = 0; i < AR; ++i) {
    int m = (BM == 128) ? (tm * 4 + (i & 3) + ((i >= 4) ? 64 : 0))
                        : (tm * AR + i);
    float4 v;
    v.x = acc[i][0] + bb.x; v.y = acc[i][1] + bb.y;
    v.z = acc[i][2] + bb.z; v.w = acc[i][3] + bb.w;
    *(float4*)(Z + (size_t)(mb + m) * N + nb + tn * 4) = v;
    psum[0] += v.x; psum[1] += v.y; psum[2] += v.z; psum[3] += v.w;
    psq[0] += v.x * v.x; psq[1] += v.y * v.y;
    psq[2] += v.z * v.z; psq[3] += v.w * v.w;
  }
  __syncthreads();
  float* red = &b_lds[0][0];                 // 2176 floats >= 2048
  int base = tm * 64 + tn * 4;
#pragma unroll
  for (int j = 0; j < 4; ++j) {
    red[base + j] = psum[j];
    red[1024 + base + j] = psq[j];
  }
  __syncthreads();
  if (tid < 64) {
    float s = 0.f, q = 0.f;
#pragma unroll
    for (int it = 0; it < 16; ++it) {
      s += red[it * 64 + tid];
      q += red[1024 + it * 64 + tid];
    }
    atomicAdd(&s_out[nb + tid], s);
    atomicAdd(&q_out[nb + tid], q);
  }
}

// ---------------------------------------------------------------------------
// Final elementwise per level: out = relu(bn1(z1)) + relu(bn2(z2))
// ---------------------------------------------------------------------------
__global__ __launch_bounds__(256)
void final_k(const float* __restrict__ z1, const float* __restrict__ z2,
             const float* __restrict__ s1, const float* __restrict__ q1,
             const float* __restrict__ g1, const float* __restrict__ be1,
             const float* __restrict__ s2, const float* __restrict__ q2,
             const float* __restrict__ g2, const float* __restrict__ be2,
             float* __restrict__ outp, int M, int C)
{
  __shared__ float sc1[256], sh1[256], sc2[256], sh2[256];
  for (int c = threadIdx.x; c < C; c += 256) {
    float mean = s1[c] / (float)M;
    float var  = q1[c] / (float)M - mean * mean;
    float r = rsqrtf(var + EPS_BN);
    sc1[c] = g1[c] * r; sh1[c] = be1[c] - mean * sc1[c];
    mean = s2[c] / (float)M;
    var  = q2[c] / (float)M - mean * mean;
    r = rsqrtf(var + EPS_BN);
    sc2[c] = g2[c] * r; sh2[c] = be2[c] - mean * sc2[c];
  }
  __syncthreads();

  int total4 = M * C / 4;
  int cmask = (C / 4) - 1;                   // C/4 is a power of two
  for (int i = blockIdx.x * 256 + threadIdx.x; i < total4; i += gridDim.x * 256) {
    int c = (i & cmask) * 4;
    float4 a = ((const float4*)z1)[i];
    float4 b = ((const float4*)z2)[i];
    float4 r;
    r.x = fmaxf(a.x * sc1[c + 0] + sh1[c + 0], 0.f) + fmaxf(b.x * sc2[c + 0] + sh2[c + 0], 0.f);
    r.y = fmaxf(a.y * sc1[c + 1] + sh1[c + 1], 0.f) + fmaxf(b.y * sc2[c + 1] + sh2[c + 1], 0.f);
    r.z = fmaxf(a.z * sc1[c + 2] + sh1[c + 2], 0.f) + fmaxf(b.z * sc2[c + 2] + sh2[c + 2], 0.f);
    r.w = fmaxf(a.w * sc1[c + 3] + sh1[c + 3], 0.f) + fmaxf(b.w * sc2[c + 3] + sh2[c + 3], 0.f);
    ((float4*)outp)[i] = r;
  }
}

// ---------------------------------------------------------------------------
extern "C" void kernel_launch(void* const* d_in, const int* in_sizes, int n_in,
                              void* d_out, int out_size, void* d_ws, size_t ws_size,
                              hipStream_t stream)
{
  const bool dict_order = (in_sizes[1] == 512 * 512);

  const float* POS[4];
  const float* X[4];
  for (int i = 0; i < 4; ++i) {
    POS[i] = (const float*)d_in[dict_order ? 3 * i : i];
    X[i]   = (const float*)d_in[dict_order ? 3 * i + 1 : 4 + i];
  }
  static const int dict_map[8] = {0, 2, 6, 3, 1, 4, 7, 5};
  auto PRM = [&](int lvl, int which) -> const float* {
    int idx = dict_order ? (12 + 8 * lvl + dict_map[which]) : (8 + 8 * lvl + which);
    return (const float*)d_in[idx];
  };

  // Workspace layout. cd/ci alias z1/z2 (L0/L1 path); L2 grid scratch also
  // lives in the z1 region (dead before L2 gemm1 writes z1; only widx, which
  // lives outside, survives). Stream order serializes all hazards.
  char* ws = (char*)d_ws;
  float* up    = (float*)(ws);                          // 16 MB max (L2)
  float* z1    = (float*)(ws + (16u << 20));            // 8 MB max
  float* z2    = (float*)(ws + (24u << 20));            // 8 MB max
  float* cd    = z1;
  int*   ci    = (int*)z2;
  float* x1o   = (float*)(ws + (32u << 20));            // 2 MB
  float* x2o   = (float*)(ws + (34u << 20));            // 4 MB
  float* stats = (float*)(ws + (38u << 20));            // 4 KB (pad 8 KB)
  float* s1 = stats, *q1 = stats + 256, *s2 = stats + 512, *q2 = stats + 768;
  float* widx  = (float*)(ws + (38u << 20) + 8192);     // 1 MB

  // grid scratch inside z1 region (<= 5.2 MB of 8 MB)
  char* gb = ws + (16u << 20);
  const size_t S = 600 * 1024;
  int*    cnt      = (int*)(gb + 0 * S);
  int*    tcnt     = (int*)(gb + 1 * S);
  int*    ofsp     = (int*)(gb + 2 * S);
  int*    tofsp    = (int*)(gb + 3 * S);
  int*    cursor   = (int*)(gb + 4 * S);
  int*    tcursor  = (int*)(gb + 5 * S);
  int*    cellstart= (int*)(gb + 6 * S);                // NCELLS+1 ints
  char*   gb2      = gb + 7 * S;
  int*    aux      = (int*)(gb2);
  int*    auxp     = (int*)(gb2 + 1024);
  int*    aux2     = (int*)(gb2 + 2048);
  int*    auxp2    = (int*)(gb2 + 3072);
  int*    pcell    = (int*)(gb2 + 4096);                        // 32 KB
  int*    tpcell   = (int*)(gb2 + 4096 + 32768);                // 128 KB
  float4* plist    = (float4*)(gb2 + 4096 + 32768 + 131072);    // 128 KB
  int*    tsorted  = (int*)(gb2 + 4096 + 32768 + 2 * 131072);   // 128 KB
  int*    ovfc     = (int*)(gb2 + 4096 + 32768 + 3 * 131072);
  int*    ovf      = (int*)(gb2 + 4096 + 32768 + 3 * 131072 + 1024); // 128 KB

  // ======================= Level 0: 512 -> 2048 ============================
  knn_part<1><<<dim3(8, 16), 256, 0, stream>>>(POS[0], POS[1], 512, 2048, 16, cd, ci);
  merge_gather<512, 0><<<32, 256, 0, stream>>>(cd, ci, 16, X[0], up, 2048, stats, nullptr);
  gemm_k<32, 1, 0><<<dim3(64, 4), 256, 0, stream>>>(
      X[1], up, 256, PRM(0, 0), PRM(0, 1),
      nullptr, nullptr, nullptr, nullptr,
      z1, s1, q1, 2048, 768, 256);
  gemm_k<32, 0, 1><<<dim3(64, 4), 256, 0, stream>>>(
      z1, nullptr, 0, PRM(0, 4), PRM(0, 5),
      s1, q1, PRM(0, 2), PRM(0, 3),
      z2, s2, q2, 2048, 256, 256);
  final_k<<<512, 256, 0, stream>>>(z1, z2, s1, q1, PRM(0, 2), PRM(0, 3),
                                   s2, q2, PRM(0, 6), PRM(0, 7), x1o, 2048, 256);

  // ======================= Level 1: 2048 -> 8192 ===========================
  knn_part<1><<<dim3(32, 32), 256, 0, stream>>>(POS[1], POS[2], 2048, 8192, 32, cd, ci);
  merge_gather<256, 0><<<128, 256, 0, stream>>>(cd, ci, 32, x1o, up, 8192, stats, nullptr);
  gemm_k<64, 1, 0><<<dim3(128, 2), 256, 0, stream>>>(
      X[2], up, 128, PRM(1, 0), PRM(1, 1),
      nullptr, nullptr, nullptr, nullptr,
      z1, s1, q1, 8192, 384, 128);
  gemm_k<64, 0, 1><<<dim3(128, 2), 256, 0, stream>>>(
      z1, nullptr, 0, PRM(1, 4), PRM(1, 5),
      s1, q1, PRM(1, 2), PRM(1, 3),
      z2, s2, q2, 8192, 128, 128);
  final_k<<<1024, 256, 0, stream>>>(z1, z2, s1, q1, PRM(1, 2), PRM(1, 3),
                                    s2, q2, PRM(1, 6), PRM(1, 7), x2o, 8192, 128);

  // ======================= Level 2: 8192 -> 32768 (grid KNN) ===============
  hipMemsetAsync(cnt, 0, 2 * S, stream);                 // cnt + tcnt
  grid_count2<<<dim3(128, 2), 256, 0, stream>>>(POS[2], 8192, cnt, pcell,
                                                POS[3], 32768, tcnt, tpcell);
  grid_scan1<<<dim3(138, 2), 256, 0, stream>>>(cnt, ofsp, aux, tcnt, tofsp, aux2);
  grid_scan2<<<2, 256, 0, stream>>>(aux, auxp, aux2, auxp2, 138);
  grid_fixup2<<<dim3(256, 2), 256, 0, stream>>>(ofsp, auxp, cursor, cellstart, 8192,
                                                tofsp, auxp2, tcursor, ovfc);
  grid_scatter2<<<dim3(128, 2), 256, 0, stream>>>(POS[2], 8192, pcell, cursor, plist,
                                                  32768, tpcell, tcursor, tsorted);
  knn_search_quad<<<512, 256, 0, stream>>>(POS[3], 32768, cellstart, plist,
                                           tsorted, widx, ovfc, ovf);
  knn_brute<<<256, 256, 0, stream>>>(POS[3], plist, 8192, ovfc, ovf, widx);
  merge_gather<128, 1><<<512, 256, 0, stream>>>(nullptr, nullptr, 0, x2o, up,
                                                32768, stats, widx);
  gemm_k<64, 1, 0><<<dim3(512, 1), 256, 0, stream>>>(
      X[3], up, 64, PRM(2, 0), PRM(2, 1),
      nullptr, nullptr, nullptr, nullptr,
      z1, s1, q1, 32768, 192, 64);
  gemm_k<64, 0, 1><<<dim3(512, 1), 256, 0, stream>>>(
      z1, nullptr, 0, PRM(2, 4), PRM(2, 5),
      s1, q1, PRM(2, 2), PRM(2, 3),
      z2, s2, q2, 32768, 64, 64);
  final_k<<<1024, 256, 0, stream>>>(z1, z2, s1, q1, PRM(2, 2), PRM(2, 3),
                                    s2, q2, PRM(2, 6), PRM(2, 7),
                                    (float*)d_out, 32768, 64);
}